// Round 7
// baseline (482.130 us; speedup 1.0000x reference)
//
#include <hip/hip_runtime.h>
#include <math.h>

#define N_TOKENS 32768
#define EMBED    2048
#define NEXP     64
#define TOPK     8
#define BM       64
#define SCS      65
#define THRESH   1e-4f
#define WELEMS   (NEXP * EMBED)
#define FIXGRID  1024

typedef __attribute__((ext_vector_type(8)))  short short8;
typedef __attribute__((ext_vector_type(4)))  short short4v;
typedef __attribute__((ext_vector_type(16))) float f32x16;

__device__ __forceinline__ unsigned short bf16rne(float f) {
  unsigned int fb = __float_as_uint(f);
  return (unsigned short)((fb + 0x7FFFu + ((fb >> 16) & 1u)) >> 16);
}

__device__ __forceinline__ void cvt4(float4 f, short4v* h, short4v* l) {
  float fs[4] = {f.x, f.y, f.z, f.w};
  short4v hh, ll;
#pragma unroll
  for (int i = 0; i < 4; ++i) {
    unsigned short hr = bf16rne(fs[i]);
    hh[i] = (short)hr;
    float hf = __uint_as_float((unsigned int)hr << 16);
    ll[i] = (short)bf16rne(fs[i] - hf);
  }
  *h = hh; *l = ll;
}

__device__ __forceinline__ void cvt8(float4 a, float4 b, short8* h, short8* l) {
  float fs[8] = {a.x, a.y, a.z, a.w, b.x, b.y, b.z, b.w};
  short8 hh, ll;
#pragma unroll
  for (int i = 0; i < 8; ++i) {
    unsigned short hr = bf16rne(fs[i]);
    hh[i] = (short)hr;
    float hf = __uint_as_float((unsigned int)hr << 16);
    ll[i] = (short)bf16rne(fs[i] - hf);
  }
  *h = hh; *l = ll;
}

// W [64,2048] fp32 -> bf16 hi/lo in MFMA B-fragment layout (R4-proven)
__global__ void split_w(const float* __restrict__ W, short* __restrict__ wh,
                        short* __restrict__ wl) {
  const int T = blockIdx.x * 256 + threadIdx.x;   // 0..16383
  const int n = T >> 8, kg8 = T & 255;
  const float4* W4 = (const float4*)W;
  float4 a = W4[n * 512 + kg8 * 2];
  float4 b = W4[n * 512 + kg8 * 2 + 1];
  short4v h0, l0, h1, l1;
  cvt4(a, &h0, &l0); cvt4(b, &h1, &l1);
  short* dh = &wh[(kg8 * 64 + n) * 8];
  short* dl = &wl[(kg8 * 64 + n) * 8];
  *(short4v*)dh = h0; *(short4v*)(dh + 4) = h1;
  *(short4v*)dl = l0; *(short4v*)(dl + 4) = l1;
}

// Barrier-free K-loop: 4 waves = 2 token-tiles x 2 K-halves; A-frags loaded
// directly from global per lane; B-frags from precomputed layout (L2-hot).
__global__ __launch_bounds__(256, 2)
void router_kernel(const float* __restrict__ x, const short* __restrict__ wh,
                   const short* __restrict__ wl, const float* __restrict__ bias,
                   int* __restrict__ gcnt, int* __restrict__ glist,
                   float* __restrict__ out) {
  __shared__ float part[2][2][64][16];   // K-half=1 partials [tt][et][lane][reg] 32 KB
  __shared__ float sc[BM * SCS];         // 16.6 KB final scores

  const int tid  = threadIdx.x;
  const int t0   = blockIdx.x * BM;
  const int lane = tid & 63;
  const int w    = tid >> 6;
  const int tt   = w & 1;          // token tile 0/1
  const int kh   = w >> 1;         // K half 0/1
  const int m    = lane & 31;      // MFMA row (token within tile) / B n within tile
  const int kq   = lane >> 5;      // k-half-of-16

  const float*  ap = x + (size_t)(t0 + tt * 32 + m) * EMBED + kh * 1024 + kq * 8;
  const short8* Bh = (const short8*)wh;
  const short8* Bl = (const short8*)wl;
  const int     b0 = (kh * 128 + kq) * 64 + m;    // et=0; et=1 at +32; step +128

  f32x16 acc0, acc1;
#pragma unroll
  for (int i = 0; i < 16; ++i) { acc0[i] = 0.f; acc1[i] = 0.f; }

  float4 a0 = *(const float4*)(ap);
  float4 a1 = *(const float4*)(ap + 4);
  short8 bh0 = Bh[b0], bl0 = Bl[b0], bh1 = Bh[b0 + 32], bl1 = Bl[b0 + 32];

#pragma unroll 4
  for (int s = 0; s < 63; ++s) {
    // prefetch step s+1 (independent; compiler pipelines with vmcnt(N))
    float4 na0 = *(const float4*)(ap + (s + 1) * 16);
    float4 na1 = *(const float4*)(ap + (s + 1) * 16 + 4);
    const int nb = b0 + (s + 1) * 128;
    short8 nbh0 = Bh[nb], nbl0 = Bl[nb], nbh1 = Bh[nb + 32], nbl1 = Bl[nb + 32];

    short8 ah, al;
    cvt8(a0, a1, &ah, &al);
    acc0 = __builtin_amdgcn_mfma_f32_32x32x16_bf16(ah, bh0, acc0, 0, 0, 0);
    acc0 = __builtin_amdgcn_mfma_f32_32x32x16_bf16(ah, bl0, acc0, 0, 0, 0);
    acc0 = __builtin_amdgcn_mfma_f32_32x32x16_bf16(al, bh0, acc0, 0, 0, 0);
    acc1 = __builtin_amdgcn_mfma_f32_32x32x16_bf16(ah, bh1, acc1, 0, 0, 0);
    acc1 = __builtin_amdgcn_mfma_f32_32x32x16_bf16(ah, bl1, acc1, 0, 0, 0);
    acc1 = __builtin_amdgcn_mfma_f32_32x32x16_bf16(al, bh1, acc1, 0, 0, 0);

    a0 = na0; a1 = na1; bh0 = nbh0; bl0 = nbl0; bh1 = nbh1; bl1 = nbl1;
  }
  {
    short8 ah, al;
    cvt8(a0, a1, &ah, &al);
    acc0 = __builtin_amdgcn_mfma_f32_32x32x16_bf16(ah, bh0, acc0, 0, 0, 0);
    acc0 = __builtin_amdgcn_mfma_f32_32x32x16_bf16(ah, bl0, acc0, 0, 0, 0);
    acc0 = __builtin_amdgcn_mfma_f32_32x32x16_bf16(al, bh0, acc0, 0, 0, 0);
    acc1 = __builtin_amdgcn_mfma_f32_32x32x16_bf16(ah, bh1, acc1, 0, 0, 0);
    acc1 = __builtin_amdgcn_mfma_f32_32x32x16_bf16(ah, bl1, acc1, 0, 0, 0);
    acc1 = __builtin_amdgcn_mfma_f32_32x32x16_bf16(al, bh1, acc1, 0, 0, 0);
  }

  // combine K-halves through LDS, then write scores
  if (kh == 1) {
#pragma unroll
    for (int r = 0; r < 4; ++r) {
      *(float4*)&part[tt][0][lane][r * 4] =
        make_float4(acc0[r * 4], acc0[r * 4 + 1], acc0[r * 4 + 2], acc0[r * 4 + 3]);
      *(float4*)&part[tt][1][lane][r * 4] =
        make_float4(acc1[r * 4], acc1[r * 4 + 1], acc1[r * 4 + 2], acc1[r * 4 + 3]);
    }
  }
  __syncthreads();
  if (kh == 0) {
#pragma unroll
    for (int reg = 0; reg < 16; ++reg) {
      const float s0 = acc0[reg] + part[tt][0][lane][reg];
      const float s1 = acc1[reg] + part[tt][1][lane][reg];
      const int row = (reg & 3) + 8 * (reg >> 2) + 4 * kq;
      sc[(tt * 32 + row) * SCS + m]      = s0;
      sc[(tt * 32 + row) * SCS + 32 + m] = s1;
    }
  }
  __syncthreads();

  float* rout = out;
  float* iout = out + (size_t)N_TOKENS * NEXP;
  const float bias_l = bias[lane];

  for (int tb = 0; tb < 4; ++tb) {
    const int tbase = w * 16 + tb * 4;
    float orig[4]; unsigned cur[4];
#pragma unroll
    for (int i = 0; i < 4; ++i) {
      orig[i] = sc[(tbase + i) * SCS + lane] + bias_l;
      unsigned b = __float_as_uint(orig[i]);
      unsigned u = b ^ (((unsigned)((int)b >> 31)) | 0x80000000u);
      cur[i] = (u & 0xFFFFFFC0u) | (63u - (unsigned)lane);
    }
    float mm[4], Z[4], ming[4], prev[4], morig[4];
    int myidx[4]; bool sel[4];
#pragma unroll
    for (int i = 0; i < 4; ++i) { sel[i] = false; morig[i] = 0.f; myidx[i] = 0; ming[i] = 1e30f; }

#pragma unroll
    for (int r = 0; r < 9; ++r) {
      unsigned v[4];
#pragma unroll
      for (int i = 0; i < 4; ++i) v[i] = cur[i];
#pragma unroll
      for (int s2 = 1; s2 < 64; s2 <<= 1) {
#pragma unroll
        for (int i = 0; i < 4; ++i) {
          unsigned o = (unsigned)__shfl_xor((int)v[i], s2);
          v[i] = v[i] > o ? v[i] : o;
        }
      }
#pragma unroll
      for (int i = 0; i < 4; ++i) {
        unsigned vb = (v[i] & 0x80000000u) ? (v[i] ^ 0x80000000u) : ~v[i];
        float fv = __uint_as_float(vb);
        if (r == 0) { mm[i] = fmaxf(fv, 0.f); Z[i] = 56.f * expf(-mm[i]) + expf(fv - mm[i]); }
        else {
          ming[i] = fminf(ming[i], prev[i] - fv);
          if (r < 8) Z[i] += expf(fv - mm[i]);
        }
        prev[i] = fv;
        if (r < 8) {
          if (lane == r) myidx[i] = 63 - (int)(v[i] & 63u);
          if (cur[i] == v[i]) { sel[i] = true; morig[i] = orig[i]; cur[i] = 0u; }
        }
      }
    }
#pragma unroll
    for (int i = 0; i < 4; ++i) {
      const int t = tbase + i;
      if (ming[i] < THRESH) {
        if (lane == 0) { int p = atomicAdd(gcnt, 1); glist[p] = t0 + t; }
      } else {
        const float p = expf(morig[i] - mm[i]) / Z[i];
        rout[(size_t)(t0 + t) * NEXP + lane] = p;
        if (lane < TOPK) iout[(size_t)(t0 + t) * TOPK + lane] = (float)myidx[i];
      }
    }
  }
}

// Exact fp64 recompute for ambiguous tokens (R6-proven)
__global__ __launch_bounds__(256, 4)
void fixup_kernel(const float* __restrict__ x, const float* __restrict__ Wf,
                  const float* __restrict__ bias, const int* __restrict__ gcnt,
                  const int* __restrict__ glist, float* __restrict__ out) {
  __shared__ float4 xsh[512];
  __shared__ double sco[NEXP];
  const int tid  = threadIdx.x;
  const int lane = tid & 63;
  const int w    = tid >> 6;
  float* rout = out;
  float* iout = out + (size_t)N_TOKENS * NEXP;
  const int cnt = *gcnt;

  for (int j = blockIdx.x; j < cnt; j += FIXGRID) {
    const int tok = glist[j];
    const float4* xr = (const float4*)x + (size_t)tok * 512;
    xsh[tid] = xr[tid];
    xsh[tid + 256] = xr[tid + 256];
    __syncthreads();

    for (int i = 0; i < 16; ++i) {
      const int e = w * 16 + i;
      const float4* wr = (const float4*)Wf + (size_t)e * 512;
      double a = 0.0;
#pragma unroll
      for (int q = 0; q < 8; ++q) {
        float4 wv = wr[q * 64 + lane];
        float4 xv = xsh[q * 64 + lane];
        a = fma((double)xv.x, (double)wv.x, a);
        a = fma((double)xv.y, (double)wv.y, a);
        a = fma((double)xv.z, (double)wv.z, a);
        a = fma((double)xv.w, (double)wv.w, a);
      }
#pragma unroll
      for (int s2 = 1; s2 < 64; s2 <<= 1) a += __shfl_xor(a, s2);
      if (lane == 0) sco[e] = a + (double)bias[e];
    }
    __syncthreads();

    if (w == 0) {
      const double orig = sco[lane];
      double curd = orig, vals[8];
      int myidx = 0; double mym = 0.0;
#pragma unroll
      for (int r = 0; r < 8; ++r) {
        double v = curd; int id = lane;
#pragma unroll
        for (int s2 = 1; s2 < 64; s2 <<= 1) {
          const double ov = __shfl_xor(v, s2);
          const int    oi = __shfl_xor(id, s2);
          if (ov > v || (ov == v && oi < id)) { v = ov; id = oi; }
        }
        vals[r] = v;
        if (lane == r)  myidx = id;
        if (lane == id) { mym = orig; curd = -1e300; }
      }
      const double md = fmax(vals[0], 0.0);
      double Zd = 56.0 * exp(-md);
#pragma unroll
      for (int r = 0; r < 8; ++r) Zd += exp(vals[r] - md);
      const double p = exp(mym - md) / Zd;
      rout[(size_t)tok * NEXP + lane] = (float)p;
      if (lane < TOPK) iout[(size_t)tok * TOPK + lane] = (float)myidx;
    }
    __syncthreads();
  }
}

extern "C" void kernel_launch(void* const* d_in, const int* in_sizes, int n_in,
                              void* d_out, int out_size, void* d_ws, size_t ws_size,
                              hipStream_t stream) {
  const float* x = (const float*)d_in[0];
  const float* W = (const float*)d_in[1];
  const float* b = (const float*)d_in[2];
  short* wh = (short*)d_ws;
  short* wl = wh + WELEMS;
  int* gcnt  = (int*)(wl + WELEMS);
  int* glist = gcnt + 4;

  hipMemsetAsync(gcnt, 0, 16, stream);
  split_w<<<64, 256, 0, stream>>>(W, wh, wl);
  router_kernel<<<N_TOKENS / BM, 256, 0, stream>>>(x, wh, wl, b, gcnt, glist,
                                                   (float*)d_out);
  fixup_kernel<<<FIXGRID, 256, 0, stream>>>(x, W, b, gcnt, glist, (float*)d_out);
}